// Round 7
// baseline (620.731 us; speedup 1.0000x reference)
//
#include <hip/hip_runtime.h>

// Problem constants
#define BB 8
#define NN 512
#define TT 64
#define SS 65      // T+1
#define DD 256
#define HH 256
#define G4 1024    // 4*H

__device__ __forceinline__ float fsigmoid(float x) {
    return __builtin_amdgcn_rcpf(1.f + __expf(-x));
}
__device__ __forceinline__ float ftanh(float x) {
    float e = __expf(2.f * x);
    return fmaf(-2.f, __builtin_amdgcn_rcpf(e + 1.f), 1.f);
}

#define PIN4(v) asm volatile("" : "+v"(v.x), "+v"(v.y), "+v"(v.z), "+v"(v.w))

// ---------------------------------------------------------------------------
// pre_kernel: blocks [0,144): xg0 = seq @ w_ih[0]^T + b_ih0 + b_hh0 (seq synth)
//             blocks [144,400): dual-feat GEMM (attn_feat, hop_feat)
//             blocks [400,1456): S0/S1 (h,tag) slot init (replay-safe)
// ---------------------------------------------------------------------------
__global__ void __launch_bounds__(256) pre_kernel(
    const float* __restrict__ lstm_in, const float* __restrict__ init_i,
    const float* __restrict__ init_h, const float* __restrict__ w_ih,
    const float* __restrict__ b_ih, const float* __restrict__ b_hh,
    float* __restrict__ xg0,
    const float* __restrict__ attn_mem, const float* __restrict__ attn_wm,
    const float* __restrict__ hop_wm,
    float* __restrict__ attn_feat, float* __restrict__ hop_feat,
    unsigned long long* __restrict__ S0, unsigned long long* __restrict__ S1)
{
    const int tid = threadIdx.x;
    const int blk = blockIdx.x;
    if (blk >= 400) {
        int i = (blk - 400) * 256 + tid;   // [0, 270336)
        if (i < 2048) {
            S0[i] = (1ULL << 32) | (unsigned long long)(unsigned)__float_as_uint(init_h[i & 255]);
        } else if (i < 4096) {
            S1[i - 2048] = (1ULL << 32)
                         | (unsigned long long)(unsigned)__float_as_uint(init_h[HH + (i & 255)]);
        } else if (i < 4096 + 65 * 2048) {
            S0[2048 + (i - 4096)] = 0ULL;
        } else if (i < 4096 + 130 * 2048) {
            S1[2048 + (i - (4096 + 65 * 2048))] = 0ULL;
        }
        return;
    }
    __shared__ __align__(16) float smem[3264];
    const int tm = (tid >> 4) * 4, tn = (tid & 15) * 4;
    const int arow = tid >> 2, akq = (tid & 3) << 2;

    if (blk < 144) {
        float* As = smem;          // [16][68]
        float* Bs = smem + 1088;
        const int bm = (blk % 9) * 64, bn = (blk / 9) * 64;
        float acc[4][4] = {};
        for (int k0 = 0; k0 < 256; k0 += 16) {
            {
                int m = bm + arow;
                float4 v = make_float4(0.f, 0.f, 0.f, 0.f);
                if (m < 520) {
                    int s = m % 65, b = m / 65;
                    const float* src = (s == 0) ? (init_i + k0 + akq)
                        : (lstm_in + ((size_t)b * TT + (s - 1)) * DD + k0 + akq);
                    v = *(const float4*)src;
                }
                As[(akq + 0) * 68 + arow] = v.x; As[(akq + 1) * 68 + arow] = v.y;
                As[(akq + 2) * 68 + arow] = v.z; As[(akq + 3) * 68 + arow] = v.w;
            }
            {
                int n = bn + arow;
                float4 v = *(const float4*)(w_ih + (size_t)n * 256 + k0 + akq);
                Bs[(akq + 0) * 68 + (n - bn)] = v.x; Bs[(akq + 1) * 68 + (n - bn)] = v.y;
                Bs[(akq + 2) * 68 + (n - bn)] = v.z; Bs[(akq + 3) * 68 + (n - bn)] = v.w;
            }
            __syncthreads();
#pragma unroll
            for (int kk = 0; kk < 16; ++kk) {
                float4 a = *(const float4*)&As[kk * 68 + tm];
                float4 b = *(const float4*)&Bs[kk * 68 + tn];
                float av[4] = {a.x, a.y, a.z, a.w};
                float bv[4] = {b.x, b.y, b.z, b.w};
#pragma unroll
                for (int i = 0; i < 4; ++i)
#pragma unroll
                    for (int jj = 0; jj < 4; ++jj)
                        acc[i][jj] = fmaf(av[i], bv[jj], acc[i][jj]);
            }
            __syncthreads();
        }
        float bad[4];
#pragma unroll
        for (int jj = 0; jj < 4; ++jj)
            bad[jj] = b_ih[bn + tn + jj] + b_hh[bn + tn + jj];
#pragma unroll
        for (int i = 0; i < 4; ++i) {
            int m = bm + tm + i;
            if (m < 520)
                *(float4*)(xg0 + (size_t)m * 1024 + bn + tn) =
                    make_float4(acc[i][0] + bad[0], acc[i][1] + bad[1],
                                acc[i][2] + bad[2], acc[i][3] + bad[3]);
        }
    } else {
        float* As  = smem;
        float* Bs  = smem + 1088;
        float* Bs2 = smem + 2176;
        const int tileid = blk - 144;                 // 0..255
        const int bm = (tileid & 63) * 64, bn = (tileid >> 6) * 64;
        float acc1[4][4] = {}, acc2[4][4] = {};
        for (int k0 = 0; k0 < 256; k0 += 16) {
            float4 va = *(const float4*)(attn_mem + (size_t)(bm + arow) * 256 + k0 + akq);
            As[(akq + 0) * 68 + arow] = va.x; As[(akq + 1) * 68 + arow] = va.y;
            As[(akq + 2) * 68 + arow] = va.z; As[(akq + 3) * 68 + arow] = va.w;
            int kk = tid >> 4, nq = (tid & 15) << 2;
            *(float4*)&Bs[kk * 68 + nq]  = *(const float4*)(attn_wm + (size_t)(k0 + kk) * 256 + bn + nq);
            *(float4*)&Bs2[kk * 68 + nq] = *(const float4*)(hop_wm  + (size_t)(k0 + kk) * 256 + bn + nq);
            __syncthreads();
#pragma unroll
            for (int kk2 = 0; kk2 < 16; ++kk2) {
                float4 a  = *(const float4*)&As[kk2 * 68 + tm];
                float4 b1 = *(const float4*)&Bs[kk2 * 68 + tn];
                float4 b2 = *(const float4*)&Bs2[kk2 * 68 + tn];
                float av[4] = {a.x, a.y, a.z, a.w};
                float b1v[4] = {b1.x, b1.y, b1.z, b1.w};
                float b2v[4] = {b2.x, b2.y, b2.z, b2.w};
#pragma unroll
                for (int i = 0; i < 4; ++i)
#pragma unroll
                    for (int jj = 0; jj < 4; ++jj) {
                        acc1[i][jj] = fmaf(av[i], b1v[jj], acc1[i][jj]);
                        acc2[i][jj] = fmaf(av[i], b2v[jj], acc2[i][jj]);
                    }
            }
            __syncthreads();
        }
#pragma unroll
        for (int i = 0; i < 4; ++i) {
            int m = bm + tm + i;
            *(float4*)(attn_feat + (size_t)m * 256 + bn + tn) =
                make_float4(acc1[i][0], acc1[i][1], acc1[i][2], acc1[i][3]);
            *(float4*)(hop_feat + (size_t)m * 256 + bn + tn) =
                make_float4(acc2[i][0], acc2[i][1], acc2[i][2], acc2[i][3]);
        }
    }
}

// ---------------------------------------------------------------------------
// batched poll of 8 adjacent (h,tag) u64 slots -> 8 floats to LDS
// ---------------------------------------------------------------------------
__device__ __forceinline__ void poll8(const unsigned long long* __restrict__ p,
                                      unsigned want, float* __restrict__ dst) {
    unsigned long long v[8];
#pragma unroll
    for (int k = 0; k < 8; ++k)
        v[k] = __hip_atomic_load(p + k, __ATOMIC_RELAXED, __HIP_MEMORY_SCOPE_AGENT);
    for (;;) {
        bool ok = true;
#pragma unroll
        for (int k = 0; k < 8; ++k) ok &= ((unsigned)(v[k] >> 32) == want);
        if (ok) break;
#pragma unroll
        for (int k = 0; k < 8; ++k)
            v[k] = __hip_atomic_load(p + k, __ATOMIC_RELAXED, __HIP_MEMORY_SCOPE_AGENT);
    }
#pragma unroll
    for (int k = 0; k < 8; ++k) dst[k] = __uint_as_float((unsigned)v[k]);
}

// dual-set variant: issue both sets, retire together (layer1)
__device__ __forceinline__ void poll8x2(const unsigned long long* __restrict__ p0, unsigned want0,
                                        const unsigned long long* __restrict__ p1, unsigned want1,
                                        float* __restrict__ d0, float* __restrict__ d1) {
    unsigned long long v0[8], v1[8];
#pragma unroll
    for (int k = 0; k < 8; ++k)
        v0[k] = __hip_atomic_load(p0 + k, __ATOMIC_RELAXED, __HIP_MEMORY_SCOPE_AGENT);
#pragma unroll
    for (int k = 0; k < 8; ++k)
        v1[k] = __hip_atomic_load(p1 + k, __ATOMIC_RELAXED, __HIP_MEMORY_SCOPE_AGENT);
    for (;;) {
        bool ok = true;
#pragma unroll
        for (int k = 0; k < 8; ++k) ok &= ((unsigned)(v0[k] >> 32) == want0);
#pragma unroll
        for (int k = 0; k < 8; ++k) ok &= ((unsigned)(v1[k] >> 32) == want1);
        if (ok) break;
#pragma unroll
        for (int k = 0; k < 8; ++k)
            v0[k] = __hip_atomic_load(p0 + k, __ATOMIC_RELAXED, __HIP_MEMORY_SCOPE_AGENT);
#pragma unroll
        for (int k = 0; k < 8; ++k)
            v1[k] = __hip_atomic_load(p1 + k, __ATOMIC_RELAXED, __HIP_MEMORY_SCOPE_AGENT);
    }
#pragma unroll
    for (int k = 0; k < 8; ++k) d0[k] = __uint_as_float((unsigned)v0[k]);
#pragma unroll
    for (int k = 0; k < 8; ++k) d1[k] = __uint_as_float((unsigned)v1[k]);
}

// ---------------------------------------------------------------------------
// persistent 2-layer LSTM, 96 blocks x 256 threads (4 waves/CU, 1 wave/EU ->
// 512-VGPR budget). Each thread: 4 weight rows x 64 k = 256 floats in VGPRs.
// lane: b=bits0-2, seg(k-quarter)=bits3-4, rhi=bit5; rows via wave index.
// Reduce over seg: shfl_xor 8,16. blocks[0,32): layer0 8j; [32,96): layer1 4j.
// ---------------------------------------------------------------------------
__global__ void __launch_bounds__(256, 1)
__attribute__((amdgpu_waves_per_eu(1, 1)))
lstm_kernel(
    const float* __restrict__ w_ih, const float* __restrict__ w_hh,
    const float* __restrict__ b_ih, const float* __restrict__ b_hh,
    const float* __restrict__ xg0, const float* __restrict__ init_c,
    unsigned long long* __restrict__ S0, unsigned long long* __restrict__ S1,
    float* __restrict__ query)
{
    __shared__ __align__(16) float smem[4416];
    const int tid  = threadIdx.x;
    const int blk  = blockIdx.x;
    const int lane = tid & 63;
    const int wv   = tid >> 6;           // 0..3
    const int b    = lane & 7;
    const int seg  = (lane >> 3) & 3;    // k-quarter
    const int rhi  = lane >> 5;          // 0..1
    const int k0   = seg * 64;
    const int sb   = tid >> 5;           // staging b   (slots tid*8..tid*8+7)
    const int sh   = (tid * 8) & 255;    // staging h
    const int fb   = tid & 7;

    if (blk < 32) {
        // ------------------------ layer 0 (8 j) ------------------------
        const int j0 = blk * 8;
        const int gate = wv;
        float4 w[4][16];
#pragma unroll
        for (int rl = 0; rl < 4; ++rl) {
            const float4* wr = (const float4*)(w_hh
                + (size_t)(gate * HH + j0 + rhi * 4 + rl) * HH + k0);
#pragma unroll
            for (int k = 0; k < 16; ++k) w[rl][k] = wr[k];
        }
#pragma unroll
        for (int rl = 0; rl < 4; ++rl)
#pragma unroll
            for (int k = 0; k < 16; ++k) PIN4(w[rl][k]);

        float* hls  = smem;            // 8*260
        float* part = smem + 2080;     // 256: [r 32][b 8]
        const int fj = tid >> 3;       // finisher (tid<64): j index 0..7
        float creg = (tid < 64) ? init_c[j0 + fj] : 0.f;
        float* const dst = &hls[sb * 260 + sh];
        const float4* const hp = (const float4*)&hls[b * 260 + k0];

        for (int t = 0; t < SS; ++t) {
            float xg[4];
            if (tid < 64) {
                const float* xp = xg0 + ((size_t)fb * SS + t) * G4 + (j0 + fj);
#pragma unroll
                for (int gg = 0; gg < 4; ++gg) xg[gg] = xp[gg * 256];
            }
            poll8(S0 + (size_t)t * 2048 + tid * 8, (unsigned)(t + 1), dst);
            __syncthreads();
            float4 hv[16];
#pragma unroll
            for (int k = 0; k < 16; ++k) hv[k] = hp[k];
            float acc[4];
#pragma unroll
            for (int rl = 0; rl < 4; ++rl) {
                float4 s4 = make_float4(0.f, 0.f, 0.f, 0.f);
#pragma unroll
                for (int k = 0; k < 16; ++k) {
                    s4.x = fmaf(w[rl][k].x, hv[k].x, s4.x);
                    s4.y = fmaf(w[rl][k].y, hv[k].y, s4.y);
                    s4.z = fmaf(w[rl][k].z, hv[k].z, s4.z);
                    s4.w = fmaf(w[rl][k].w, hv[k].w, s4.w);
                }
                acc[rl] = (s4.x + s4.y) + (s4.z + s4.w);
            }
#pragma unroll
            for (int rl = 0; rl < 4; ++rl) {
                acc[rl] += __shfl_xor(acc[rl], 8, 64);
                acc[rl] += __shfl_xor(acc[rl], 16, 64);
            }
            if (seg == 0) {
#pragma unroll
                for (int rl = 0; rl < 4; ++rl)
                    part[(wv * 8 + rhi * 4 + rl) * 8 + b] = acc[rl];
            }
            __syncthreads();
            if (tid < 64) {
                float gv[4];
#pragma unroll
                for (int gg = 0; gg < 4; ++gg)
                    gv[gg] = xg[gg] + part[(gg * 8 + fj) * 8 + fb];
                float c = fsigmoid(gv[1]) * creg + fsigmoid(gv[0]) * ftanh(gv[2]);
                float h = fsigmoid(gv[3]) * ftanh(c);
                creg = c;
                unsigned long long u = ((unsigned long long)(unsigned)(t + 2) << 32)
                                     | (unsigned long long)(unsigned)__float_as_uint(h);
                __hip_atomic_store(S0 + (size_t)(t + 1) * 2048 + fb * 256 + (j0 + fj), u,
                                   __ATOMIC_RELAXED, __HIP_MEMORY_SCOPE_AGENT);
            }
        }
    } else {
        // ------------------------ layer 1 (4 j) ------------------------
        const int j0 = (blk - 32) * 4;
        const int half = wv >> 1;                  // 0: w_ih1 on h0new, 1: w_hh1 on h1
        const int gate = (wv & 1) * 2 + rhi;
        float4 w[4][16];
        {
            const float* wb = half ? w_hh : w_ih;
#pragma unroll
            for (int rl = 0; rl < 4; ++rl) {
                const float4* wr = (const float4*)(wb
                    + (size_t)(G4 + gate * HH + j0 + rl) * HH + k0);
#pragma unroll
                for (int k = 0; k < 16; ++k) w[rl][k] = wr[k];
            }
        }
#pragma unroll
        for (int rl = 0; rl < 4; ++rl)
#pragma unroll
            for (int k = 0; k < 16; ++k) PIN4(w[rl][k]);

        float* hls0 = smem;            // 8*260
        float* hls1 = smem + 2080;     // 8*260
        float* part = smem + 4160;     // 256: [r 32][b 8], r = half*16+gate*4+jl
        const int fj = tid >> 3;       // finisher (tid<32): j 0..3
        float creg = 0.f, bias[4] = {0.f, 0.f, 0.f, 0.f};
        if (tid < 32) {
            creg = init_c[HH + j0 + fj];
#pragma unroll
            for (int gg = 0; gg < 4; ++gg)
                bias[gg] = b_ih[G4 + gg * HH + j0 + fj] + b_hh[G4 + gg * HH + j0 + fj];
        }
        float* const dst0 = &hls0[sb * 260 + sh];
        float* const dst1 = &hls1[sb * 260 + sh];
        const float4* const hp = (const float4*)&((half ? hls1 : hls0)[b * 260 + k0]);

        for (int t = 0; t < SS; ++t) {
            poll8x2(S0 + (size_t)(t + 1) * 2048 + tid * 8, (unsigned)(t + 2),
                    S1 + (size_t)t * 2048 + tid * 8, (unsigned)(t + 1), dst0, dst1);
            __syncthreads();
            float4 hv[16];
#pragma unroll
            for (int k = 0; k < 16; ++k) hv[k] = hp[k];
            float acc[4];
#pragma unroll
            for (int rl = 0; rl < 4; ++rl) {
                float4 s4 = make_float4(0.f, 0.f, 0.f, 0.f);
#pragma unroll
                for (int k = 0; k < 16; ++k) {
                    s4.x = fmaf(w[rl][k].x, hv[k].x, s4.x);
                    s4.y = fmaf(w[rl][k].y, hv[k].y, s4.y);
                    s4.z = fmaf(w[rl][k].z, hv[k].z, s4.z);
                    s4.w = fmaf(w[rl][k].w, hv[k].w, s4.w);
                }
                acc[rl] = (s4.x + s4.y) + (s4.z + s4.w);
            }
#pragma unroll
            for (int rl = 0; rl < 4; ++rl) {
                acc[rl] += __shfl_xor(acc[rl], 8, 64);
                acc[rl] += __shfl_xor(acc[rl], 16, 64);
            }
            if (seg == 0) {
#pragma unroll
                for (int rl = 0; rl < 4; ++rl)
                    part[(wv * 8 + rhi * 4 + rl) * 8 + b] = acc[rl];
            }
            __syncthreads();
            if (tid < 32) {
                float gv[4];
#pragma unroll
                for (int gg = 0; gg < 4; ++gg)
                    gv[gg] = bias[gg] + part[(gg * 4 + fj) * 8 + fb]
                                      + part[(16 + gg * 4 + fj) * 8 + fb];
                float c = fsigmoid(gv[1]) * creg + fsigmoid(gv[0]) * ftanh(gv[2]);
                float h = fsigmoid(gv[3]) * ftanh(c);
                creg = c;
                int jj = j0 + fj;
                unsigned long long u = ((unsigned long long)(unsigned)(t + 2) << 32)
                                     | (unsigned long long)(unsigned)__float_as_uint(h);
                __hip_atomic_store(S1 + (size_t)(t + 1) * 2048 + fb * 256 + jj, u,
                                   __ATOMIC_RELAXED, __HIP_MEMORY_SCOPE_AGENT);
                query[((size_t)fb * SS + t) * HH + jj] = h;
            }
        }
    }
}

// ---------------------------------------------------------------------------
// small fp32 GEMM (64x64 tile), C = A[M,K] @ B[K,N]   (q1 / q2)
// ---------------------------------------------------------------------------
__global__ void __launch_bounds__(256) gemm_kernel(
    const float* __restrict__ A, const float* __restrict__ B,
    float* __restrict__ C, int M, int N, int K)
{
    __shared__ __align__(16) float As[16 * 68];
    __shared__ __align__(16) float Bs[16 * 68];
    const int tid = threadIdx.x;
    const int bm = blockIdx.x * 64, bn = blockIdx.y * 64;
    const int tm = (tid >> 4) * 4, tn = (tid & 15) * 4;
    const int arow = tid >> 2, akq = (tid & 3) << 2;
    float acc[4][4] = {};
    for (int k0 = 0; k0 < K; k0 += 16) {
        {
            int m = bm + arow;
            float4 v = make_float4(0.f, 0.f, 0.f, 0.f);
            if (m < M) v = *(const float4*)(A + (size_t)m * K + k0 + akq);
            As[(akq + 0) * 68 + arow] = v.x; As[(akq + 1) * 68 + arow] = v.y;
            As[(akq + 2) * 68 + arow] = v.z; As[(akq + 3) * 68 + arow] = v.w;
        }
        {
            int kk = tid >> 4, nq = (tid & 15) << 2;
            *(float4*)&Bs[kk * 68 + nq] = *(const float4*)(B + (size_t)(k0 + kk) * N + bn + nq);
        }
        __syncthreads();
#pragma unroll
        for (int kk2 = 0; kk2 < 16; ++kk2) {
            float4 a = *(const float4*)&As[kk2 * 68 + tm];
            float4 b = *(const float4*)&Bs[kk2 * 68 + tn];
            float av[4] = {a.x, a.y, a.z, a.w};
            float bv[4] = {b.x, b.y, b.z, b.w};
#pragma unroll
            for (int i = 0; i < 4; ++i)
#pragma unroll
                for (int jj = 0; jj < 4; ++jj)
                    acc[i][jj] = fmaf(av[i], bv[jj], acc[i][jj]);
        }
        __syncthreads();
    }
#pragma unroll
    for (int i = 0; i < 4; ++i) {
        int m = bm + tm + i;
        if (m < M)
            *(float4*)(C + (size_t)m * N + bn + tn) =
                make_float4(acc[i][0], acc[i][1], acc[i][2], acc[i][3]);
    }
}

// ---------------------------------------------------------------------------
// additive score, s-tiled + exp-factorized:
//   out[b,s,n] = Vsum - 2 * sum_h v[h] / (e^{2 feat[b,n,h]} * e^{2 q[b,s,h]} + 1)
// ---------------------------------------------------------------------------
__global__ void __launch_bounds__(256) score2_kernel(
    const float* __restrict__ feat, const float* __restrict__ qv,
    const float* __restrict__ v, const int* __restrict__ mem_sizes,
    float* __restrict__ outp, int masked)
{
    const int nt = blockIdx.x, st = blockIdx.y, b = blockIdx.z;
    const int tid = threadIdx.x;
    const int n0 = nt * 64, s0 = st * 13;
    const int msize = masked ? mem_sizes[b] : NN;
    if (n0 >= msize) return;
    __shared__ float efls[32 * 261];
    __shared__ float eqls[13 * 261];
    __shared__ float vls[256];

    vls[tid] = v[tid];
    for (int k = 0; k < 13; ++k)
        eqls[k * 261 + tid] = __expf(2.f * qv[((size_t)b * SS + s0 + k) * HH + tid]);
    __syncthreads();
    float vsum = 0.f;
    {
        float p0 = 0.f, p1 = 0.f, p2 = 0.f, p3 = 0.f;
#pragma unroll
        for (int h = 0; h < 256; h += 4) {
            p0 += vls[h]; p1 += vls[h + 1]; p2 += vls[h + 2]; p3 += vls[h + 3];
        }
        vsum = (p0 + p1) + (p2 + p3);
    }

    for (int c = 0; c < 2; ++c) {
        const int nbase = n0 + c * 32;
        int nrows = msize - nbase; nrows = nrows < 0 ? 0 : (nrows > 32 ? 32 : nrows);
        __syncthreads();
        for (int k = 0; k < nrows; ++k)
            efls[k * 261 + tid] = __expf(2.f * feat[((size_t)b * NN + nbase + k) * HH + tid]);
        __syncthreads();
#pragma unroll
        for (int i = 0; i < 2; ++i) {
            int p = i * 256 + tid;
            if (p < 416) {
                int s = p >> 5, nl = p & 31;
                if (nl < nrows) {
                    const float* ef = &efls[nl * 261];
                    const float* eq = &eqls[s * 261];
                    float acc = 0.f;
#pragma unroll 4
                    for (int h = 0; h < 256; ++h)
                        acc = fmaf(vls[h],
                                   __builtin_amdgcn_rcpf(fmaf(ef[h], eq[h], 1.f)),
                                   acc);
                    outp[((size_t)b * SS + s0 + s) * NN + (nbase + nl)] =
                        fmaf(-2.f, acc, vsum);
                }
            }
        }
    }
}

// ---------------------------------------------------------------------------
// fused softmax + weighted sum per (b, s-tile of 13)
// ---------------------------------------------------------------------------
__global__ void __launch_bounds__(256) smwsum_kernel(
    const float* __restrict__ sc, const float* __restrict__ feat,
    const int* __restrict__ mem_sizes, float* __restrict__ q2raw)
{
    const int st = blockIdx.x, b = blockIdx.y;
    const int tid = threadIdx.x;
    const int s0 = st * 13;
    const int msize = mem_sizes[b];
    __shared__ float pls[13 * 520];
    for (int i = tid; i < 13 * 512; i += 256) {
        int s = i >> 9, n = i & 511;
        pls[s * 520 + n] = (n < msize)
            ? sc[((size_t)b * SS + s0 + s) * NN + n] : -3e38f;
    }
    __syncthreads();
    const int lane = tid & 63, wv = tid >> 6;
    for (int r = wv; r < 13; r += 4) {
        float x[8];
        float m = -3e38f;
#pragma unroll
        for (int k = 0; k < 8; ++k) {
            x[k] = pls[r * 520 + lane + 64 * k];
            m = fmaxf(m, x[k]);
        }
#pragma unroll
        for (int off = 32; off; off >>= 1) m = fmaxf(m, __shfl_xor(m, off, 64));
        float l = 0.f;
#pragma unroll
        for (int k = 0; k < 8; ++k) { x[k] = __expf(x[k] - m); l += x[k]; }
#pragma unroll
        for (int off = 32; off; off >>= 1) l += __shfl_xor(l, off, 64);
        float inv = __builtin_amdgcn_rcpf(l);
#pragma unroll
        for (int k = 0; k < 8; ++k) pls[r * 520 + lane + 64 * k] = x[k] * inv;
    }
    __syncthreads();
    float acc[13];
#pragma unroll
    for (int s = 0; s < 13; ++s) acc[s] = 0.f;
    const float* fb = feat + (size_t)b * NN * HH + tid;
    int n = 0;
    for (; n + 2 <= msize; n += 2) {
        float f0 = fb[(size_t)n * HH];
        float f1 = fb[(size_t)(n + 1) * HH];
#pragma unroll
        for (int s = 0; s < 13; ++s) {
            acc[s] = fmaf(pls[s * 520 + n], f0, acc[s]);
            acc[s] = fmaf(pls[s * 520 + n + 1], f1, acc[s]);
        }
    }
    if (n < msize) {
        float f0 = fb[(size_t)n * HH];
#pragma unroll
        for (int s = 0; s < 13; ++s) acc[s] = fmaf(pls[s * 520 + n], f0, acc[s]);
    }
#pragma unroll
    for (int s = 0; s < 13; ++s)
        q2raw[((size_t)b * SS + s0 + s) * HH + tid] = acc[s];
}

// ---------------------------------------------------------------------------
extern "C" void kernel_launch(void* const* d_in, const int* in_sizes, int n_in,
                              void* d_out, int out_size, void* d_ws, size_t ws_size,
                              hipStream_t stream) {
    const float* attn_mem  = (const float*)d_in[0];
    const int*   mem_sizes = (const int*)d_in[1];
    const float* lstm_in   = (const float*)d_in[2];
    const float* init_h    = (const float*)d_in[3];
    const float* init_c    = (const float*)d_in[4];
    const float* init_i    = (const float*)d_in[5];
    const float* w_ih      = (const float*)d_in[6];
    const float* w_hh      = (const float*)d_in[7];
    const float* b_ih      = (const float*)d_in[8];
    const float* b_hh      = (const float*)d_in[9];
    const float* attn_wm   = (const float*)d_in[10];
    const float* attn_wq   = (const float*)d_in[11];
    const float* attn_v    = (const float*)d_in[12];
    const float* hop_wm    = (const float*)d_in[13];
    const float* hop_wq    = (const float*)d_in[14];
    const float* hop_v     = (const float*)d_in[15];
    float* out = (float*)d_out;

    float* ws        = (float*)d_ws;
    float* attn_feat = ws;                 // 1,048,576 floats
    float* hop_feat  = ws + 1048576;       // 1,048,576
    float* xg0       = ws + 2097152;       //   532,480
    float* query     = ws + 2629632;       //   133,120
    // overlaid region (lstm phase vs post phase)
    float* region    = ws + 2762752;
    unsigned long long* S0 = (unsigned long long*)region;            // 135,168 u64
    unsigned long long* S1 = (unsigned long long*)(region + 270336); // 135,168 u64
    float* q1     = region;                // 133,120 (S dead by then)
    float* sc     = region + 133120;       // 266,240
    float* q2raw  = region + 399360;       // 133,120
    float* q2     = region + 532480;       // 133,120

    pre_kernel<<<1456, 256, 0, stream>>>(lstm_in, init_i, init_h, w_ih, b_ih, b_hh,
                                         xg0, attn_mem, attn_wm, hop_wm,
                                         attn_feat, hop_feat, S0, S1);
    {
        void* args[] = { (void*)&w_ih, (void*)&w_hh, (void*)&b_ih, (void*)&b_hh,
                         (void*)&xg0, (void*)&init_c, (void*)&S0, (void*)&S1,
                         (void*)&query };
        hipLaunchCooperativeKernel(lstm_kernel, dim3(96), dim3(256), args, 0u, stream);
    }
    gemm_kernel<<<dim3(9, 4), 256, 0, stream>>>(query, hop_wq, q1, 520, 256, 256);
    score2_kernel<<<dim3(8, 5, 8), 256, 0, stream>>>(hop_feat, q1, hop_v,
                                                     mem_sizes, sc, 1);
    smwsum_kernel<<<dim3(5, 8), 256, 0, stream>>>(sc, hop_feat, mem_sizes, q2raw);
    gemm_kernel<<<dim3(9, 4), 256, 0, stream>>>(q2raw, attn_wq, q2, 520, 256, 256);
    score2_kernel<<<dim3(8, 5, 8), 256, 0, stream>>>(attn_feat, q2, attn_v,
                                                     mem_sizes, out, 0);
}

// Round 8
// 393.949 us; speedup vs baseline: 1.5757x; 1.5757x over previous
//
#include <hip/hip_runtime.h>

// Problem constants
#define BB 8
#define NN 512
#define TT 64
#define SS 65      // T+1
#define DD 256
#define HH 256
#define G4 1024    // 4*H

// fast transcendentals (v_rcp_f32 based, ~1e-5 rel err; saturate at +-inf)
__device__ __forceinline__ float fsigmoid(float x) {
    return __builtin_amdgcn_rcpf(1.f + __expf(-x));
}
__device__ __forceinline__ float ftanh(float x) {
    float e = __expf(2.f * x);
    return fmaf(-2.f, __builtin_amdgcn_rcpf(e + 1.f), 1.f);
}

// ---------------------------------------------------------------------------
// pre_kernel: blocks [0,144): xg0 = seq @ w_ih[0]^T + b_ih0 + b_hh0 (seq synth)
//             blocks [144,400): dual-feat GEMM (attn_feat, hop_feat)
//             blocks [400,1456): S0/S1 (h,tag) slot init (replay-safe)
// ---------------------------------------------------------------------------
__global__ void __launch_bounds__(256) pre_kernel(
    const float* __restrict__ lstm_in, const float* __restrict__ init_i,
    const float* __restrict__ init_h, const float* __restrict__ w_ih,
    const float* __restrict__ b_ih, const float* __restrict__ b_hh,
    float* __restrict__ xg0,
    const float* __restrict__ attn_mem, const float* __restrict__ attn_wm,
    const float* __restrict__ hop_wm,
    float* __restrict__ attn_feat, float* __restrict__ hop_feat,
    unsigned long long* __restrict__ S0, unsigned long long* __restrict__ S1)
{
    const int tid = threadIdx.x;
    const int blk = blockIdx.x;
    if (blk >= 400) {
        int i = (blk - 400) * 256 + tid;   // [0, 270336)
        if (i < 2048) {
            S0[i] = (1ULL << 32) | (unsigned long long)(unsigned)__float_as_uint(init_h[i & 255]);
        } else if (i < 4096) {
            S1[i - 2048] = (1ULL << 32)
                         | (unsigned long long)(unsigned)__float_as_uint(init_h[HH + (i & 255)]);
        } else if (i < 4096 + 65 * 2048) {
            S0[2048 + (i - 4096)] = 0ULL;
        } else if (i < 4096 + 130 * 2048) {
            S1[2048 + (i - (4096 + 65 * 2048))] = 0ULL;
        }
        return;
    }
    __shared__ __align__(16) float smem[3264];
    const int tm = (tid >> 4) * 4, tn = (tid & 15) * 4;
    const int arow = tid >> 2, akq = (tid & 3) << 2;

    if (blk < 144) {
        float* As = smem;          // [16][68]
        float* Bs = smem + 1088;
        const int bm = (blk % 9) * 64, bn = (blk / 9) * 64;
        float acc[4][4] = {};
        for (int k0 = 0; k0 < 256; k0 += 16) {
            {
                int m = bm + arow;
                float4 v = make_float4(0.f, 0.f, 0.f, 0.f);
                if (m < 520) {
                    int s = m % 65, b = m / 65;
                    const float* src = (s == 0) ? (init_i + k0 + akq)
                        : (lstm_in + ((size_t)b * TT + (s - 1)) * DD + k0 + akq);
                    v = *(const float4*)src;
                }
                As[(akq + 0) * 68 + arow] = v.x; As[(akq + 1) * 68 + arow] = v.y;
                As[(akq + 2) * 68 + arow] = v.z; As[(akq + 3) * 68 + arow] = v.w;
            }
            {
                int n = bn + arow;
                float4 v = *(const float4*)(w_ih + (size_t)n * 256 + k0 + akq);
                Bs[(akq + 0) * 68 + (n - bn)] = v.x; Bs[(akq + 1) * 68 + (n - bn)] = v.y;
                Bs[(akq + 2) * 68 + (n - bn)] = v.z; Bs[(akq + 3) * 68 + (n - bn)] = v.w;
            }
            __syncthreads();
#pragma unroll
            for (int kk = 0; kk < 16; ++kk) {
                float4 a = *(const float4*)&As[kk * 68 + tm];
                float4 b = *(const float4*)&Bs[kk * 68 + tn];
                float av[4] = {a.x, a.y, a.z, a.w};
                float bv[4] = {b.x, b.y, b.z, b.w};
#pragma unroll
                for (int i = 0; i < 4; ++i)
#pragma unroll
                    for (int jj = 0; jj < 4; ++jj)
                        acc[i][jj] = fmaf(av[i], bv[jj], acc[i][jj]);
            }
            __syncthreads();
        }
        float bad[4];
#pragma unroll
        for (int jj = 0; jj < 4; ++jj)
            bad[jj] = b_ih[bn + tn + jj] + b_hh[bn + tn + jj];
#pragma unroll
        for (int i = 0; i < 4; ++i) {
            int m = bm + tm + i;
            if (m < 520)
                *(float4*)(xg0 + (size_t)m * 1024 + bn + tn) =
                    make_float4(acc[i][0] + bad[0], acc[i][1] + bad[1],
                                acc[i][2] + bad[2], acc[i][3] + bad[3]);
        }
    } else {
        float* As  = smem;
        float* Bs  = smem + 1088;
        float* Bs2 = smem + 2176;
        const int tileid = blk - 144;                 // 0..255
        const int bm = (tileid & 63) * 64, bn = (tileid >> 6) * 64;
        float acc1[4][4] = {}, acc2[4][4] = {};
        for (int k0 = 0; k0 < 256; k0 += 16) {
            float4 va = *(const float4*)(attn_mem + (size_t)(bm + arow) * 256 + k0 + akq);
            As[(akq + 0) * 68 + arow] = va.x; As[(akq + 1) * 68 + arow] = va.y;
            As[(akq + 2) * 68 + arow] = va.z; As[(akq + 3) * 68 + arow] = va.w;
            int kk = tid >> 4, nq = (tid & 15) << 2;
            *(float4*)&Bs[kk * 68 + nq]  = *(const float4*)(attn_wm + (size_t)(k0 + kk) * 256 + bn + nq);
            *(float4*)&Bs2[kk * 68 + nq] = *(const float4*)(hop_wm  + (size_t)(k0 + kk) * 256 + bn + nq);
            __syncthreads();
#pragma unroll
            for (int kk2 = 0; kk2 < 16; ++kk2) {
                float4 a  = *(const float4*)&As[kk2 * 68 + tm];
                float4 b1 = *(const float4*)&Bs[kk2 * 68 + tn];
                float4 b2 = *(const float4*)&Bs2[kk2 * 68 + tn];
                float av[4] = {a.x, a.y, a.z, a.w};
                float b1v[4] = {b1.x, b1.y, b1.z, b1.w};
                float b2v[4] = {b2.x, b2.y, b2.z, b2.w};
#pragma unroll
                for (int i = 0; i < 4; ++i)
#pragma unroll
                    for (int jj = 0; jj < 4; ++jj) {
                        acc1[i][jj] = fmaf(av[i], b1v[jj], acc1[i][jj]);
                        acc2[i][jj] = fmaf(av[i], b2v[jj], acc2[i][jj]);
                    }
            }
            __syncthreads();
        }
#pragma unroll
        for (int i = 0; i < 4; ++i) {
            int m = bm + tm + i;
            *(float4*)(attn_feat + (size_t)m * 256 + bn + tn) =
                make_float4(acc1[i][0], acc1[i][1], acc1[i][2], acc1[i][3]);
            *(float4*)(hop_feat + (size_t)m * 256 + bn + tn) =
                make_float4(acc2[i][0], acc2[i][1], acc2[i][2], acc2[i][3]);
        }
    }
}

// ---------------------------------------------------------------------------
// persistent 2-layer LSTM, data-as-flag sync (R3 structure, measured 158us).
// 96 blocks x 1024 threads. Weights re-read through L1 each step (the
// compiler's remat choice at 8 waves/SIMD is empirically the best point).
// ---------------------------------------------------------------------------
__device__ __forceinline__ float dot16(const float4* w, const float* hp) {
    float4 s = make_float4(0.f, 0.f, 0.f, 0.f);
#pragma unroll
    for (int k = 0; k < 16; ++k) {
        float4 h4 = *(const float4*)(hp + 4 * k);
        s.x = fmaf(w[k].x, h4.x, s.x);
        s.y = fmaf(w[k].y, h4.y, s.y);
        s.z = fmaf(w[k].z, h4.z, s.z);
        s.w = fmaf(w[k].w, h4.w, s.w);
    }
    return (s.x + s.y) + (s.z + s.w);
}

__device__ __forceinline__ float poll_h(const unsigned long long* p, unsigned want) {
    unsigned long long u = __hip_atomic_load(p, __ATOMIC_RELAXED, __HIP_MEMORY_SCOPE_AGENT);
    while ((unsigned)(u >> 32) != want) {
        u = __hip_atomic_load(p, __ATOMIC_RELAXED, __HIP_MEMORY_SCOPE_AGENT);
    }
    return __uint_as_float((unsigned)u);
}

__global__ void __launch_bounds__(1024, 4) lstm_kernel(
    const float* __restrict__ w_ih, const float* __restrict__ w_hh,
    const float* __restrict__ b_ih, const float* __restrict__ b_hh,
    const float* __restrict__ xg0, const float* __restrict__ init_c,
    unsigned long long* __restrict__ S0, unsigned long long* __restrict__ S1,
    float* __restrict__ query)
{
    __shared__ float hls[64 * 68];
    __shared__ float part[1024];
    const int tid = threadIdx.x;
    const int blk = blockIdx.x;
    // staging map (thread tid stages payload pair 2tid, 2tid+1)
    const int g = tid * 2;
    const int sb = g >> 8, r0 = g & 255, sg0 = r0 >> 6, kq = r0 & 63;
    float* const dst = &hls[(sg0 * 8 + sb) * 68 + kq];

    if (blk < 32) {
        // ------------------------ layer 0 ------------------------
        const int jl = tid & 7, gate = (tid >> 3) & 3, b = (tid >> 5) & 7, seg = tid >> 8;
        const int j0 = blk * 8, j = j0 + jl;
        float4 w[16];
        {
            const float4* wr = (const float4*)(w_hh + (size_t)(gate * HH + j) * HH + seg * 64);
#pragma unroll
            for (int k = 0; k < 16; ++k) w[k] = wr[k];
        }
        const int fj = tid >> 3, fb = tid & 7;   // finisher mapping (tid<64)
        float creg = (tid < 64) ? init_c[j0 + fj] : 0.f;
        const int chunk = seg * 8 + b;
        const int pidx = (chunk * 8 + jl) * 4 + gate;

        for (int t = 0; t < SS; ++t) {
            float xg[4];
            if (tid < 64) {
                const float* xp = xg0 + ((size_t)fb * SS + t) * G4 + (j0 + fj);
#pragma unroll
                for (int gg = 0; gg < 4; ++gg) xg[gg] = xp[gg * 256];
            }
            {   // poll+stage h0^{t} (tag t+1)
                const unsigned long long* src = S0 + (size_t)t * 2048 + g;
                dst[0] = poll_h(src, (unsigned)(t + 1));
                dst[1] = poll_h(src + 1, (unsigned)(t + 1));
            }
            __syncthreads();
            part[pidx] = dot16(w, &hls[chunk * 68]);
            __syncthreads();
            if (tid < 64) {
                float g0 = xg[0], g1 = xg[1], g2 = xg[2], g3 = xg[3];
#pragma unroll
                for (int s2 = 0; s2 < 4; ++s2) {
                    const float* pp = &part[((s2 * 8 + fb) * 8 + fj) * 4];
                    g0 += pp[0]; g1 += pp[1]; g2 += pp[2]; g3 += pp[3];
                }
                float c = fsigmoid(g1) * creg + fsigmoid(g0) * ftanh(g2);
                float h = fsigmoid(g3) * ftanh(c);
                creg = c;
                unsigned long long u = ((unsigned long long)(unsigned)(t + 2) << 32)
                                     | (unsigned long long)(unsigned)__float_as_uint(h);
                __hip_atomic_store(S0 + (size_t)(t + 1) * 2048 + fb * 256 + (j0 + fj), u,
                                   __ATOMIC_RELAXED, __HIP_MEMORY_SCOPE_AGENT);
            }
        }
    } else {
        // ------------------------ layer 1 ------------------------
        const int jl = tid & 3, gate = (tid >> 2) & 3, b = (tid >> 4) & 7, seg = tid >> 7;
        const int j0 = (blk - 32) * 4, j = j0 + jl;
        float4 w[16];
        {
            const float* base = (seg < 4)
                ? (w_ih + (size_t)(G4 + gate * HH + j) * HH + seg * 64)
                : (w_hh + (size_t)(G4 + gate * HH + j) * HH + (seg - 4) * 64);
            const float4* wr = (const float4*)base;
#pragma unroll
            for (int k = 0; k < 16; ++k) w[k] = wr[k];
        }
        const int fj = tid >> 3, fb = tid & 7;   // finisher mapping (tid<32)
        float creg = 0.f, bias[4] = {0.f, 0.f, 0.f, 0.f};
        if (tid < 32) {
            creg = init_c[HH + j0 + fj];
#pragma unroll
            for (int gg = 0; gg < 4; ++gg)
                bias[gg] = b_ih[G4 + gg * HH + j0 + fj] + b_hh[G4 + gg * HH + j0 + fj];
        }
        const int chunk = seg * 8 + b;
        const int pidx = chunk * 16 + jl * 4 + gate;

        for (int t = 0; t < SS; ++t) {
            {   // poll+stage h0^{t+1} (tag t+2) -> chunks 0..31
                const unsigned long long* src = S0 + (size_t)(t + 1) * 2048 + g;
                dst[0] = poll_h(src, (unsigned)(t + 2));
                dst[1] = poll_h(src + 1, (unsigned)(t + 2));
            }
            __syncthreads();
            if (seg < 4) part[pidx] = dot16(w, &hls[chunk * 68]);
            {   // poll+stage h1^{t} (tag t+1) -> chunks 32..63
                const unsigned long long* src = S1 + (size_t)t * 2048 + g;
                float v0 = poll_h(src, (unsigned)(t + 1));
                float v1 = poll_h(src + 1, (unsigned)(t + 1));
                dst[32 * 68 + 0] = v0;
                dst[32 * 68 + 1] = v1;
            }
            __syncthreads();
            if (seg >= 4) part[pidx] = dot16(w, &hls[chunk * 68]);  // chunk in 32..63
            __syncthreads();
            if (tid < 32) {
                float g0 = bias[0], g1 = bias[1], g2 = bias[2], g3 = bias[3];
#pragma unroll
                for (int s2 = 0; s2 < 8; ++s2) {
                    const float* pp = &part[(s2 * 8 + fb) * 16 + fj * 4];
                    g0 += pp[0]; g1 += pp[1]; g2 += pp[2]; g3 += pp[3];
                }
                float c = fsigmoid(g1) * creg + fsigmoid(g0) * ftanh(g2);
                float h = fsigmoid(g3) * ftanh(c);
                creg = c;
                int jj = j0 + fj;
                unsigned long long u = ((unsigned long long)(unsigned)(t + 2) << 32)
                                     | (unsigned long long)(unsigned)__float_as_uint(h);
                __hip_atomic_store(S1 + (size_t)(t + 1) * 2048 + fb * 256 + jj, u,
                                   __ATOMIC_RELAXED, __HIP_MEMORY_SCOPE_AGENT);
                query[((size_t)fb * SS + t) * HH + jj] = h;
            }
        }
    }
}

// ---------------------------------------------------------------------------
// small fp32 GEMM (64x64 tile), C = A[M,K] @ B[K,N]   (q1 / q2)
// ---------------------------------------------------------------------------
__global__ void __launch_bounds__(256) gemm_kernel(
    const float* __restrict__ A, const float* __restrict__ B,
    float* __restrict__ C, int M, int N, int K)
{
    __shared__ __align__(16) float As[16 * 68];
    __shared__ __align__(16) float Bs[16 * 68];
    const int tid = threadIdx.x;
    const int bm = blockIdx.x * 64, bn = blockIdx.y * 64;
    const int tm = (tid >> 4) * 4, tn = (tid & 15) * 4;
    const int arow = tid >> 2, akq = (tid & 3) << 2;
    float acc[4][4] = {};
    for (int k0 = 0; k0 < K; k0 += 16) {
        {
            int m = bm + arow;
            float4 v = make_float4(0.f, 0.f, 0.f, 0.f);
            if (m < M) v = *(const float4*)(A + (size_t)m * K + k0 + akq);
            As[(akq + 0) * 68 + arow] = v.x; As[(akq + 1) * 68 + arow] = v.y;
            As[(akq + 2) * 68 + arow] = v.z; As[(akq + 3) * 68 + arow] = v.w;
        }
        {
            int kk = tid >> 4, nq = (tid & 15) << 2;
            *(float4*)&Bs[kk * 68 + nq] = *(const float4*)(B + (size_t)(k0 + kk) * N + bn + nq);
        }
        __syncthreads();
#pragma unroll
        for (int kk2 = 0; kk2 < 16; ++kk2) {
            float4 a = *(const float4*)&As[kk2 * 68 + tm];
            float4 b = *(const float4*)&Bs[kk2 * 68 + tn];
            float av[4] = {a.x, a.y, a.z, a.w};
            float bv[4] = {b.x, b.y, b.z, b.w};
#pragma unroll
            for (int i = 0; i < 4; ++i)
#pragma unroll
                for (int jj = 0; jj < 4; ++jj)
                    acc[i][jj] = fmaf(av[i], bv[jj], acc[i][jj]);
        }
        __syncthreads();
    }
#pragma unroll
    for (int i = 0; i < 4; ++i) {
        int m = bm + tm + i;
        if (m < M)
            *(float4*)(C + (size_t)m * N + bn + tn) =
                make_float4(acc[i][0], acc[i][1], acc[i][2], acc[i][3]);
    }
}

// ---------------------------------------------------------------------------
// additive score, s-tiled by 5 (one feat load serves 5 s-rows):
//   out[b,s,n] = sum_h tanh(feat[b,n,h] + q[b,s,h]) * v[h]
// grid (2 n-halves, 13 s-tiles, 8 b); wave-per-n shfl reduce (R3 structure).
// ---------------------------------------------------------------------------
__global__ void __launch_bounds__(256) score5_kernel(
    const float* __restrict__ feat, const float* __restrict__ q,
    const float* __restrict__ v, const int* __restrict__ mem_sizes,
    float* __restrict__ out, int masked)
{
    const int nt = blockIdx.x, st = blockIdx.y, b = blockIdx.z;
    const int tid = threadIdx.x;
    const int s0 = st * 5;
    const int n0 = nt * 256;
    __shared__ float qs[5][256], vs[256];
    vs[tid] = v[tid];
#pragma unroll
    for (int k = 0; k < 5; ++k)
        qs[k][tid] = q[((size_t)b * SS + s0 + k) * HH + tid];
    __syncthreads();
    const int msize = masked ? mem_sizes[b] : NN;
    float* ob = out + ((size_t)b * SS + s0) * NN;
    if (masked) {
        int n = n0 + tid;
        if (n >= msize) {
#pragma unroll
            for (int k = 0; k < 5; ++k) ob[(size_t)k * NN + n] = -1e18f;
        }
    }
    const int lane = tid & 63, wv = tid >> 6;
    float4 v4 = *(const float4*)&vs[lane << 2];
    float4 q4[5];
#pragma unroll
    for (int k = 0; k < 5; ++k) q4[k] = *(const float4*)&qs[k][lane << 2];
    const float* fb = feat + (size_t)b * NN * HH + (lane << 2);
    const int nend = (msize < n0 + 256) ? msize : (n0 + 256);
    for (int n = n0 + wv; n < nend; n += 4) {
        float4 f4 = *(const float4*)(fb + (size_t)n * HH);
        float a[5];
#pragma unroll
        for (int k = 0; k < 5; ++k) {
            a[k] = ftanh(f4.x + q4[k].x) * v4.x + ftanh(f4.y + q4[k].y) * v4.y
                 + ftanh(f4.z + q4[k].z) * v4.z + ftanh(f4.w + q4[k].w) * v4.w;
        }
#pragma unroll
        for (int off = 32; off; off >>= 1) {
#pragma unroll
            for (int k = 0; k < 5; ++k) a[k] += __shfl_xor(a[k], off, 64);
        }
        if (lane == 0) {
#pragma unroll
            for (int k = 0; k < 5; ++k) ob[(size_t)k * NN + n] = a[k];
        }
    }
}

// ---------------------------------------------------------------------------
// fused softmax + weighted sum (R3 structure, measured good):
//   query2[b,s,h] = softmax_n(score[b,s,:]) @ feat[b,:,h], 5 s-rows per block
// ---------------------------------------------------------------------------
__global__ void __launch_bounds__(256) swsum_kernel(
    const float* __restrict__ score, const float* __restrict__ feat,
    const int* __restrict__ mem_sizes, float* __restrict__ out)
{
    const int b = blockIdx.y, s0 = blockIdx.x * 5;
    const int tid = threadIdx.x;
    __shared__ float ns[5][512];
    for (int i = tid; i < 5 * 512; i += 256)
        ns[i >> 9][i & 511] = score[((size_t)b * SS + s0 + (i >> 9)) * NN + (i & 511)];
    __syncthreads();
    const int wv = tid >> 6, lane = tid & 63;
    for (int r2 = wv; r2 < 5; r2 += 4) {
        float vv[8];
#pragma unroll
        for (int k = 0; k < 8; ++k) vv[k] = ns[r2][lane + 64 * k];
        float m = vv[0];
#pragma unroll
        for (int k = 1; k < 8; ++k) m = fmaxf(m, vv[k]);
#pragma unroll
        for (int off = 32; off; off >>= 1) m = fmaxf(m, __shfl_xor(m, off, 64));
        float l = 0.f;
#pragma unroll
        for (int k = 0; k < 8; ++k) { vv[k] = __expf(vv[k] - m); l += vv[k]; }
#pragma unroll
        for (int off = 32; off; off >>= 1) l += __shfl_xor(l, off, 64);
        float inv = __builtin_amdgcn_rcpf(l);
#pragma unroll
        for (int k = 0; k < 8; ++k) ns[r2][lane + 64 * k] = vv[k] * inv;
    }
    __syncthreads();
    const int msize = mem_sizes[b];
    const int nmax = (msize + 3) & ~3;
    float a0 = 0.f, a1 = 0.f, a2 = 0.f, a3 = 0.f, a4 = 0.f;
    const float* fb = feat + (size_t)b * NN * HH + tid;
    for (int n = 0; n < nmax; n += 4) {
        float f0 = fb[(size_t)(n + 0) * HH];
        float f1 = fb[(size_t)(n + 1) * HH];
        float f2 = fb[(size_t)(n + 2) * HH];
        float f3 = fb[(size_t)(n + 3) * HH];
        a0 += ns[0][n] * f0 + ns[0][n + 1] * f1 + ns[0][n + 2] * f2 + ns[0][n + 3] * f3;
        a1 += ns[1][n] * f0 + ns[1][n + 1] * f1 + ns[1][n + 2] * f2 + ns[1][n + 3] * f3;
        a2 += ns[2][n] * f0 + ns[2][n + 1] * f1 + ns[2][n + 2] * f2 + ns[2][n + 3] * f3;
        a3 += ns[3][n] * f0 + ns[3][n + 1] * f1 + ns[3][n + 2] * f2 + ns[3][n + 3] * f3;
        a4 += ns[4][n] * f0 + ns[4][n + 1] * f1 + ns[4][n + 2] * f2 + ns[4][n + 3] * f3;
    }
    out[((size_t)b * SS + s0 + 0) * HH + tid] = a0;
    out[((size_t)b * SS + s0 + 1) * HH + tid] = a1;
    out[((size_t)b * SS + s0 + 2) * HH + tid] = a2;
    out[((size_t)b * SS + s0 + 3) * HH + tid] = a3;
    out[((size_t)b * SS + s0 + 4) * HH + tid] = a4;
}

// ---------------------------------------------------------------------------
extern "C" void kernel_launch(void* const* d_in, const int* in_sizes, int n_in,
                              void* d_out, int out_size, void* d_ws, size_t ws_size,
                              hipStream_t stream) {
    const float* attn_mem  = (const float*)d_in[0];
    const int*   mem_sizes = (const int*)d_in[1];
    const float* lstm_in   = (const float*)d_in[2];
    const float* init_h    = (const float*)d_in[3];
    const float* init_c    = (const float*)d_in[4];
    const float* init_i    = (const float*)d_in[5];
    const float* w_ih      = (const float*)d_in[6];
    const float* w_hh      = (const float*)d_in[7];
    const float* b_ih      = (const float*)d_in[8];
    const float* b_hh      = (const float*)d_in[9];
    const float* attn_wm   = (const float*)d_in[10];
    const float* attn_wq   = (const float*)d_in[11];
    const float* attn_v    = (const float*)d_in[12];
    const float* hop_wm    = (const float*)d_in[13];
    const float* hop_wq    = (const float*)d_in[14];
    const float* hop_v     = (const float*)d_in[15];
    float* out = (float*)d_out;

    float* ws        = (float*)d_ws;
    float* attn_feat = ws;                 // 1,048,576 floats
    float* hop_feat  = ws + 1048576;       // 1,048,576
    float* xg0       = ws + 2097152;       //   532,480
    float* query     = ws + 2629632;       //   133,120
    // overlaid region (lstm phase vs post phase)
    float* region    = ws + 2762752;
    unsigned long long* S0 = (unsigned long long*)region;            // 135,168 u64
    unsigned long long* S1 = (unsigned long long*)(region + 270336); // 135,168 u64
    float* q1     = region;                // 133,120 (S dead by then)
    float* sc     = region + 133120;       // 266,240
    float* q2raw  = region + 399360;       // 133,120
    float* q2     = region + 532480;       // 133,120

    pre_kernel<<<1456, 256, 0, stream>>>(lstm_in, init_i, init_h, w_ih, b_ih, b_hh,
                                         xg0, attn_mem, attn_wm, hop_wm,
                                         attn_feat, hop_feat, S0, S1);
    {
        void* args[] = { (void*)&w_ih, (void*)&w_hh, (void*)&b_ih, (void*)&b_hh,
                         (void*)&xg0, (void*)&init_c, (void*)&S0, (void*)&S1,
                         (void*)&query };
        hipLaunchCooperativeKernel(lstm_kernel, dim3(96), dim3(1024), args, 0u, stream);
    }
    gemm_kernel<<<dim3(9, 4), 256, 0, stream>>>(query, hop_wq, q1, 520, 256, 256);
    score5_kernel<<<dim3(2, 13, 8), 256, 0, stream>>>(hop_feat, q1, hop_v,
                                                      mem_sizes, sc, 1);
    swsum_kernel<<<dim3(13, 8), 256, 0, stream>>>(sc, hop_feat, mem_sizes, q2raw);
    gemm_kernel<<<dim3(9, 4), 256, 0, stream>>>(q2raw, attn_wq, q2, 520, 256, 256);
    score5_kernel<<<dim3(2, 13, 8), 256, 0, stream>>>(attn_feat, q2, attn_v,
                                                      mem_sizes, out, 0);
}

// Round 9
// 285.709 us; speedup vs baseline: 2.1726x; 1.3788x over previous
//
#include <hip/hip_runtime.h>

// Problem constants
#define BB 8
#define NN 512
#define TT 64
#define SS 65      // T+1
#define DD 256
#define HH 256
#define G4 1024    // 4*H

// fast transcendentals (v_rcp_f32 based, ~1e-5 rel err; saturate at +-inf)
__device__ __forceinline__ float fsigmoid(float x) {
    return __builtin_amdgcn_rcpf(1.f + __expf(-x));
}
__device__ __forceinline__ float ftanh(float x) {
    float e = __expf(2.f * x);
    return fmaf(-2.f, __builtin_amdgcn_rcpf(e + 1.f), 1.f);
}

// ---------------------------------------------------------------------------
// pre_kernel: blocks [0,144): xg0 = seq @ w_ih[0]^T + b_ih0 + b_hh0 (seq synth)
//             blocks [144,400): dual-feat GEMM (attn_feat, hop_feat)
//             blocks [400,1456): S0/S1 (h,tag) slot init (replay-safe)
// ---------------------------------------------------------------------------
__global__ void __launch_bounds__(256) pre_kernel(
    const float* __restrict__ lstm_in, const float* __restrict__ init_i,
    const float* __restrict__ init_h, const float* __restrict__ w_ih,
    const float* __restrict__ b_ih, const float* __restrict__ b_hh,
    float* __restrict__ xg0,
    const float* __restrict__ attn_mem, const float* __restrict__ attn_wm,
    const float* __restrict__ hop_wm,
    float* __restrict__ attn_feat, float* __restrict__ hop_feat,
    unsigned long long* __restrict__ S0, unsigned long long* __restrict__ S1)
{
    const int tid = threadIdx.x;
    const int blk = blockIdx.x;
    if (blk >= 400) {
        int i = (blk - 400) * 256 + tid;   // [0, 270336)
        if (i < 2048) {
            S0[i] = (1ULL << 32) | (unsigned long long)(unsigned)__float_as_uint(init_h[i & 255]);
        } else if (i < 4096) {
            S1[i - 2048] = (1ULL << 32)
                         | (unsigned long long)(unsigned)__float_as_uint(init_h[HH + (i & 255)]);
        } else if (i < 4096 + 65 * 2048) {
            S0[2048 + (i - 4096)] = 0ULL;
        } else if (i < 4096 + 130 * 2048) {
            S1[2048 + (i - (4096 + 65 * 2048))] = 0ULL;
        }
        return;
    }
    __shared__ __align__(16) float smem[3264];
    const int tm = (tid >> 4) * 4, tn = (tid & 15) * 4;
    const int arow = tid >> 2, akq = (tid & 3) << 2;

    if (blk < 144) {
        float* As = smem;          // [16][68]
        float* Bs = smem + 1088;
        const int bm = (blk % 9) * 64, bn = (blk / 9) * 64;
        float acc[4][4] = {};
        for (int k0 = 0; k0 < 256; k0 += 16) {
            {
                int m = bm + arow;
                float4 v = make_float4(0.f, 0.f, 0.f, 0.f);
                if (m < 520) {
                    int s = m % 65, b = m / 65;
                    const float* src = (s == 0) ? (init_i + k0 + akq)
                        : (lstm_in + ((size_t)b * TT + (s - 1)) * DD + k0 + akq);
                    v = *(const float4*)src;
                }
                As[(akq + 0) * 68 + arow] = v.x; As[(akq + 1) * 68 + arow] = v.y;
                As[(akq + 2) * 68 + arow] = v.z; As[(akq + 3) * 68 + arow] = v.w;
            }
            {
                int n = bn + arow;
                float4 v = *(const float4*)(w_ih + (size_t)n * 256 + k0 + akq);
                Bs[(akq + 0) * 68 + (n - bn)] = v.x; Bs[(akq + 1) * 68 + (n - bn)] = v.y;
                Bs[(akq + 2) * 68 + (n - bn)] = v.z; Bs[(akq + 3) * 68 + (n - bn)] = v.w;
            }
            __syncthreads();
#pragma unroll
            for (int kk = 0; kk < 16; ++kk) {
                float4 a = *(const float4*)&As[kk * 68 + tm];
                float4 b = *(const float4*)&Bs[kk * 68 + tn];
                float av[4] = {a.x, a.y, a.z, a.w};
                float bv[4] = {b.x, b.y, b.z, b.w};
#pragma unroll
                for (int i = 0; i < 4; ++i)
#pragma unroll
                    for (int jj = 0; jj < 4; ++jj)
                        acc[i][jj] = fmaf(av[i], bv[jj], acc[i][jj]);
            }
            __syncthreads();
        }
        float bad[4];
#pragma unroll
        for (int jj = 0; jj < 4; ++jj)
            bad[jj] = b_ih[bn + tn + jj] + b_hh[bn + tn + jj];
#pragma unroll
        for (int i = 0; i < 4; ++i) {
            int m = bm + tm + i;
            if (m < 520)
                *(float4*)(xg0 + (size_t)m * 1024 + bn + tn) =
                    make_float4(acc[i][0] + bad[0], acc[i][1] + bad[1],
                                acc[i][2] + bad[2], acc[i][3] + bad[3]);
        }
    } else {
        float* As  = smem;
        float* Bs  = smem + 1088;
        float* Bs2 = smem + 2176;
        const int tileid = blk - 144;                 // 0..255
        const int bm = (tileid & 63) * 64, bn = (tileid >> 6) * 64;
        float acc1[4][4] = {}, acc2[4][4] = {};
        for (int k0 = 0; k0 < 256; k0 += 16) {
            float4 va = *(const float4*)(attn_mem + (size_t)(bm + arow) * 256 + k0 + akq);
            As[(akq + 0) * 68 + arow] = va.x; As[(akq + 1) * 68 + arow] = va.y;
            As[(akq + 2) * 68 + arow] = va.z; As[(akq + 3) * 68 + arow] = va.w;
            int kk = tid >> 4, nq = (tid & 15) << 2;
            *(float4*)&Bs[kk * 68 + nq]  = *(const float4*)(attn_wm + (size_t)(k0 + kk) * 256 + bn + nq);
            *(float4*)&Bs2[kk * 68 + nq] = *(const float4*)(hop_wm  + (size_t)(k0 + kk) * 256 + bn + nq);
            __syncthreads();
#pragma unroll
            for (int kk2 = 0; kk2 < 16; ++kk2) {
                float4 a  = *(const float4*)&As[kk2 * 68 + tm];
                float4 b1 = *(const float4*)&Bs[kk2 * 68 + tn];
                float4 b2 = *(const float4*)&Bs2[kk2 * 68 + tn];
                float av[4] = {a.x, a.y, a.z, a.w};
                float b1v[4] = {b1.x, b1.y, b1.z, b1.w};
                float b2v[4] = {b2.x, b2.y, b2.z, b2.w};
#pragma unroll
                for (int i = 0; i < 4; ++i)
#pragma unroll
                    for (int jj = 0; jj < 4; ++jj) {
                        acc1[i][jj] = fmaf(av[i], b1v[jj], acc1[i][jj]);
                        acc2[i][jj] = fmaf(av[i], b2v[jj], acc2[i][jj]);
                    }
            }
            __syncthreads();
        }
#pragma unroll
        for (int i = 0; i < 4; ++i) {
            int m = bm + tm + i;
            *(float4*)(attn_feat + (size_t)m * 256 + bn + tn) =
                make_float4(acc1[i][0], acc1[i][1], acc1[i][2], acc1[i][3]);
            *(float4*)(hop_feat + (size_t)m * 256 + bn + tn) =
                make_float4(acc2[i][0], acc2[i][1], acc2[i][2], acc2[i][3]);
        }
    }
}

// ---------------------------------------------------------------------------
// persistent 2-layer LSTM, data-as-flag sync (R3 structure, measured 158us).
// 96 blocks x 1024 threads. UNCHANGED from R8.
// ---------------------------------------------------------------------------
__device__ __forceinline__ float dot16(const float4* w, const float* hp) {
    float4 s = make_float4(0.f, 0.f, 0.f, 0.f);
#pragma unroll
    for (int k = 0; k < 16; ++k) {
        float4 h4 = *(const float4*)(hp + 4 * k);
        s.x = fmaf(w[k].x, h4.x, s.x);
        s.y = fmaf(w[k].y, h4.y, s.y);
        s.z = fmaf(w[k].z, h4.z, s.z);
        s.w = fmaf(w[k].w, h4.w, s.w);
    }
    return (s.x + s.y) + (s.z + s.w);
}

__device__ __forceinline__ float poll_h(const unsigned long long* p, unsigned want) {
    unsigned long long u = __hip_atomic_load(p, __ATOMIC_RELAXED, __HIP_MEMORY_SCOPE_AGENT);
    while ((unsigned)(u >> 32) != want) {
        u = __hip_atomic_load(p, __ATOMIC_RELAXED, __HIP_MEMORY_SCOPE_AGENT);
    }
    return __uint_as_float((unsigned)u);
}

__global__ void __launch_bounds__(1024, 4) lstm_kernel(
    const float* __restrict__ w_ih, const float* __restrict__ w_hh,
    const float* __restrict__ b_ih, const float* __restrict__ b_hh,
    const float* __restrict__ xg0, const float* __restrict__ init_c,
    unsigned long long* __restrict__ S0, unsigned long long* __restrict__ S1,
    float* __restrict__ query)
{
    __shared__ float hls[64 * 68];
    __shared__ float part[1024];
    const int tid = threadIdx.x;
    const int blk = blockIdx.x;
    const int g = tid * 2;
    const int sb = g >> 8, r0 = g & 255, sg0 = r0 >> 6, kq = r0 & 63;
    float* const dst = &hls[(sg0 * 8 + sb) * 68 + kq];

    if (blk < 32) {
        // ------------------------ layer 0 ------------------------
        const int jl = tid & 7, gate = (tid >> 3) & 3, b = (tid >> 5) & 7, seg = tid >> 8;
        const int j0 = blk * 8, j = j0 + jl;
        float4 w[16];
        {
            const float4* wr = (const float4*)(w_hh + (size_t)(gate * HH + j) * HH + seg * 64);
#pragma unroll
            for (int k = 0; k < 16; ++k) w[k] = wr[k];
        }
        const int fj = tid >> 3, fb = tid & 7;   // finisher mapping (tid<64)
        float creg = (tid < 64) ? init_c[j0 + fj] : 0.f;
        const int chunk = seg * 8 + b;
        const int pidx = (chunk * 8 + jl) * 4 + gate;

        for (int t = 0; t < SS; ++t) {
            float xg[4];
            if (tid < 64) {
                const float* xp = xg0 + ((size_t)fb * SS + t) * G4 + (j0 + fj);
#pragma unroll
                for (int gg = 0; gg < 4; ++gg) xg[gg] = xp[gg * 256];
            }
            {   // poll+stage h0^{t} (tag t+1)
                const unsigned long long* src = S0 + (size_t)t * 2048 + g;
                dst[0] = poll_h(src, (unsigned)(t + 1));
                dst[1] = poll_h(src + 1, (unsigned)(t + 1));
            }
            __syncthreads();
            part[pidx] = dot16(w, &hls[chunk * 68]);
            __syncthreads();
            if (tid < 64) {
                float g0 = xg[0], g1 = xg[1], g2 = xg[2], g3 = xg[3];
#pragma unroll
                for (int s2 = 0; s2 < 4; ++s2) {
                    const float* pp = &part[((s2 * 8 + fb) * 8 + fj) * 4];
                    g0 += pp[0]; g1 += pp[1]; g2 += pp[2]; g3 += pp[3];
                }
                float c = fsigmoid(g1) * creg + fsigmoid(g0) * ftanh(g2);
                float h = fsigmoid(g3) * ftanh(c);
                creg = c;
                unsigned long long u = ((unsigned long long)(unsigned)(t + 2) << 32)
                                     | (unsigned long long)(unsigned)__float_as_uint(h);
                __hip_atomic_store(S0 + (size_t)(t + 1) * 2048 + fb * 256 + (j0 + fj), u,
                                   __ATOMIC_RELAXED, __HIP_MEMORY_SCOPE_AGENT);
            }
        }
    } else {
        // ------------------------ layer 1 ------------------------
        const int jl = tid & 3, gate = (tid >> 2) & 3, b = (tid >> 4) & 7, seg = tid >> 7;
        const int j0 = (blk - 32) * 4, j = j0 + jl;
        float4 w[16];
        {
            const float* base = (seg < 4)
                ? (w_ih + (size_t)(G4 + gate * HH + j) * HH + seg * 64)
                : (w_hh + (size_t)(G4 + gate * HH + j) * HH + (seg - 4) * 64);
            const float4* wr = (const float4*)base;
#pragma unroll
            for (int k = 0; k < 16; ++k) w[k] = wr[k];
        }
        const int fj = tid >> 3, fb = tid & 7;   // finisher mapping (tid<32)
        float creg = 0.f, bias[4] = {0.f, 0.f, 0.f, 0.f};
        if (tid < 32) {
            creg = init_c[HH + j0 + fj];
#pragma unroll
            for (int gg = 0; gg < 4; ++gg)
                bias[gg] = b_ih[G4 + gg * HH + j0 + fj] + b_hh[G4 + gg * HH + j0 + fj];
        }
        const int chunk = seg * 8 + b;
        const int pidx = chunk * 16 + jl * 4 + gate;

        for (int t = 0; t < SS; ++t) {
            {   // poll+stage h0^{t+1} (tag t+2) -> chunks 0..31
                const unsigned long long* src = S0 + (size_t)(t + 1) * 2048 + g;
                dst[0] = poll_h(src, (unsigned)(t + 2));
                dst[1] = poll_h(src + 1, (unsigned)(t + 2));
            }
            __syncthreads();
            if (seg < 4) part[pidx] = dot16(w, &hls[chunk * 68]);
            {   // poll+stage h1^{t} (tag t+1) -> chunks 32..63
                const unsigned long long* src = S1 + (size_t)t * 2048 + g;
                float v0 = poll_h(src, (unsigned)(t + 1));
                float v1 = poll_h(src + 1, (unsigned)(t + 1));
                dst[32 * 68 + 0] = v0;
                dst[32 * 68 + 1] = v1;
            }
            __syncthreads();
            if (seg >= 4) part[pidx] = dot16(w, &hls[chunk * 68]);  // chunk in 32..63
            __syncthreads();
            if (tid < 32) {
                float g0 = bias[0], g1 = bias[1], g2 = bias[2], g3 = bias[3];
#pragma unroll
                for (int s2 = 0; s2 < 8; ++s2) {
                    const float* pp = &part[(s2 * 8 + fb) * 16 + fj * 4];
                    g0 += pp[0]; g1 += pp[1]; g2 += pp[2]; g3 += pp[3];
                }
                float c = fsigmoid(g1) * creg + fsigmoid(g0) * ftanh(g2);
                float h = fsigmoid(g3) * ftanh(c);
                creg = c;
                int jj = j0 + fj;
                unsigned long long u = ((unsigned long long)(unsigned)(t + 2) << 32)
                                     | (unsigned long long)(unsigned)__float_as_uint(h);
                __hip_atomic_store(S1 + (size_t)(t + 1) * 2048 + fb * 256 + jj, u,
                                   __ATOMIC_RELAXED, __HIP_MEMORY_SCOPE_AGENT);
                query[((size_t)fb * SS + t) * HH + jj] = h;
            }
        }
    }
}

// ---------------------------------------------------------------------------
// fused matvec + additive score, 512 threads (8 waves), grid (65,8):
//   qx = qin[b,s,:] @ wq                    (fused per-block matvec)
//   out[b,s,n] = sum_h tanh(feat[b,n,h] + qx[h]) * v[h]
// wave-per-n, 2-deep pipelined; masked rows written -1e18 and skipped.
// ---------------------------------------------------------------------------
__global__ void __launch_bounds__(512) score_kernel(
    const float* __restrict__ qin, const float* __restrict__ wq,
    const float* __restrict__ feat, const float* __restrict__ v,
    const int* __restrict__ mem_sizes, float* __restrict__ out, int masked)
{
    const int s = blockIdx.x, b = blockIdx.y, tid = threadIdx.x;
    __shared__ float qrow[256], vs[256];
    __shared__ float partm[512];
    if (tid < 256) qrow[tid] = qin[((size_t)b * SS + s) * HH + tid];
    else           vs[tid - 256] = v[tid - 256];
    __syncthreads();
    {   // qx = qrow @ wq  (each half-K by one group of 256 threads)
        const int kh = tid >> 8, hp2 = tid & 255;
        const float* wp = wq + (size_t)(kh * 128) * HH + hp2;
        const float* qr = qrow + kh * 128;
        float a = 0.f;
#pragma unroll 8
        for (int hh = 0; hh < 128; ++hh) a = fmaf(qr[hh], wp[(size_t)hh * HH], a);
        partm[tid] = a;
    }
    __syncthreads();
    if (tid < 256) qrow[tid] = partm[tid] + partm[tid + 256];  // qrow := qx
    __syncthreads();

    const int msize = masked ? mem_sizes[b] : NN;
    const int lane = tid & 63, wv = tid >> 6;
    float* ob = out + ((size_t)b * SS + s) * NN;
    for (int n = msize + tid; n < NN; n += 512) ob[n] = -1e18f;
    float4 q4 = *(const float4*)&qrow[lane << 2];
    float4 v4 = *(const float4*)&vs[lane << 2];
    const float* fb = feat + (size_t)b * NN * HH + (lane << 2);
    int n = wv;
    for (; n + 8 < msize; n += 16) {
        float4 fa = *(const float4*)(fb + (size_t)n * HH);
        float4 fc = *(const float4*)(fb + (size_t)(n + 8) * HH);
        float a0 = ftanh(fa.x + q4.x) * v4.x + ftanh(fa.y + q4.y) * v4.y
                 + ftanh(fa.z + q4.z) * v4.z + ftanh(fa.w + q4.w) * v4.w;
        float a1 = ftanh(fc.x + q4.x) * v4.x + ftanh(fc.y + q4.y) * v4.y
                 + ftanh(fc.z + q4.z) * v4.z + ftanh(fc.w + q4.w) * v4.w;
#pragma unroll
        for (int off = 32; off; off >>= 1) {
            a0 += __shfl_xor(a0, off, 64);
            a1 += __shfl_xor(a1, off, 64);
        }
        if (lane == 0) { ob[n] = a0; ob[n + 8] = a1; }
    }
    for (; n < msize; n += 8) {
        float4 fa = *(const float4*)(fb + (size_t)n * HH);
        float a0 = ftanh(fa.x + q4.x) * v4.x + ftanh(fa.y + q4.y) * v4.y
                 + ftanh(fa.z + q4.z) * v4.z + ftanh(fa.w + q4.w) * v4.w;
#pragma unroll
        for (int off = 32; off; off >>= 1) a0 += __shfl_xor(a0, off, 64);
        if (lane == 0) ob[n] = a0;
    }
}

// ---------------------------------------------------------------------------
// fused softmax + weighted sum, 512 threads (8 waves), grid (13,8):
//   p = softmax_n(sc[b,s,:]) (masked); q2raw[b,s,h] = sum_n p[n]*feat[b,n,h]
// wave w owns n-stripe [64w,64w+64); partials reduced via LDS.
// ---------------------------------------------------------------------------
__global__ void __launch_bounds__(512) swsum8_kernel(
    const float* __restrict__ sc, const float* __restrict__ feat,
    const int* __restrict__ mem_sizes, float* __restrict__ q2raw)
{
    const int st = blockIdx.x, b = blockIdx.y, tid = threadIdx.x;
    const int s0 = st * 5;
    const int msize = mem_sizes[b];
    __shared__ float pls[5 * 520];
    __shared__ float partw[8 * 5 * 256];   // 40 KB
    for (int i = tid; i < 5 * 512; i += 512) {
        int s = i >> 9, n = i & 511;
        pls[s * 520 + n] = (n < msize)
            ? sc[((size_t)b * SS + s0 + s) * NN + n] : -3e38f;
    }
    __syncthreads();
    const int lane = tid & 63, wv = tid >> 6;
    if (wv < 5) {
        const int r = wv;
        float x[8];
        float m = -3e38f;
#pragma unroll
        for (int k = 0; k < 8; ++k) {
            x[k] = pls[r * 520 + lane + 64 * k];
            m = fmaxf(m, x[k]);
        }
#pragma unroll
        for (int off = 32; off; off >>= 1) m = fmaxf(m, __shfl_xor(m, off, 64));
        float l = 0.f;
#pragma unroll
        for (int k = 0; k < 8; ++k) { x[k] = __expf(x[k] - m); l += x[k]; }
#pragma unroll
        for (int off = 32; off; off >>= 1) l += __shfl_xor(l, off, 64);
        float inv = __builtin_amdgcn_rcpf(l);
#pragma unroll
        for (int k = 0; k < 8; ++k) pls[r * 520 + lane + 64 * k] = x[k] * inv;
    }
    __syncthreads();
    {   // wsum partial over this wave's n-stripe
        float4 acc[5];
#pragma unroll
        for (int s = 0; s < 5; ++s) acc[s] = make_float4(0.f, 0.f, 0.f, 0.f);
        const float* fb = feat + (size_t)b * NN * HH + (lane << 2);
        const int nb = wv * 64;
        for (int i = 0; i < 64; ++i) {
            float4 f = *(const float4*)(fb + (size_t)(nb + i) * HH);
#pragma unroll
            for (int s = 0; s < 5; ++s) {
                float p = pls[s * 520 + nb + i];
                acc[s].x = fmaf(p, f.x, acc[s].x);
                acc[s].y = fmaf(p, f.y, acc[s].y);
                acc[s].z = fmaf(p, f.z, acc[s].z);
                acc[s].w = fmaf(p, f.w, acc[s].w);
            }
        }
#pragma unroll
        for (int s = 0; s < 5; ++s)
            *(float4*)&partw[(wv * 5 + s) * 256 + (lane << 2)] = acc[s];
    }
    __syncthreads();
    for (int i = tid; i < 5 * 256; i += 512) {
        int s = i >> 8, h = i & 255;
        float r = 0.f;
#pragma unroll
        for (int w = 0; w < 8; ++w) r += partw[(w * 5 + s) * 256 + h];
        q2raw[((size_t)b * SS + s0 + s) * HH + h] = r;
    }
}

// ---------------------------------------------------------------------------
extern "C" void kernel_launch(void* const* d_in, const int* in_sizes, int n_in,
                              void* d_out, int out_size, void* d_ws, size_t ws_size,
                              hipStream_t stream) {
    const float* attn_mem  = (const float*)d_in[0];
    const int*   mem_sizes = (const int*)d_in[1];
    const float* lstm_in   = (const float*)d_in[2];
    const float* init_h    = (const float*)d_in[3];
    const float* init_c    = (const float*)d_in[4];
    const float* init_i    = (const float*)d_in[5];
    const float* w_ih      = (const float*)d_in[6];
    const float* w_hh      = (const float*)d_in[7];
    const float* b_ih      = (const float*)d_in[8];
    const float* b_hh      = (const float*)d_in[9];
    const float* attn_wm   = (const float*)d_in[10];
    const float* attn_wq   = (const float*)d_in[11];
    const float* attn_v    = (const float*)d_in[12];
    const float* hop_wm    = (const float*)d_in[13];
    const float* hop_wq    = (const float*)d_in[14];
    const float* hop_v     = (const float*)d_in[15];
    float* out = (float*)d_out;

    float* ws        = (float*)d_ws;
    float* attn_feat = ws;                 // 1,048,576 floats
    float* hop_feat  = ws + 1048576;       // 1,048,576
    float* xg0       = ws + 2097152;       //   532,480
    float* query     = ws + 2629632;       //   133,120
    // overlaid region (lstm phase vs post phase)
    float* region    = ws + 2762752;
    unsigned long long* S0 = (unsigned long long*)region;            // 135,168 u64
    unsigned long long* S1 = (unsigned long long*)(region + 270336); // 135,168 u64
    float* sc     = region;                // 266,240 (S dead by then)
    float* q2raw  = region + 266240;       // 133,120

    pre_kernel<<<1456, 256, 0, stream>>>(lstm_in, init_i, init_h, w_ih, b_ih, b_hh,
                                         xg0, attn_mem, attn_wm, hop_wm,
                                         attn_feat, hop_feat, S0, S1);
    {
        void* args[] = { (void*)&w_ih, (void*)&w_hh, (void*)&b_ih, (void*)&b_hh,
                         (void*)&xg0, (void*)&init_c, (void*)&S0, (void*)&S1,
                         (void*)&query };
        hipLaunchCooperativeKernel(lstm_kernel, dim3(96), dim3(1024), args, 0u, stream);
    }
    score_kernel<<<dim3(65, 8), 512, 0, stream>>>(query, hop_wq, hop_feat, hop_v,
                                                  mem_sizes, sc, 1);
    swsum8_kernel<<<dim3(13, 8), 512, 0, stream>>>(sc, hop_feat, mem_sizes, q2raw);
    score_kernel<<<dim3(65, 8), 512, 0, stream>>>(q2raw, attn_wq, attn_feat, attn_v,
                                                  mem_sizes, out, 0);
}